// Round 9
// baseline (387.820 us; speedup 1.0000x reference)
//
#include <hip/hip_runtime.h>
#include <hip/hip_fp16.h>
#include <cstdint>

// ---------------- CSR build: atomic-free bucketed counting sort (R7) ----------------

#define EPBH 4096   // edges per block in hist/scatter passes (256 thr x 16)
#define DCAP 9216   // LDS staging capacity in bucket_csr (mean ~8163 edges)

__global__ __launch_bounds__(256) void bucket_hist(const int* __restrict__ dst,
                                                   int* __restrict__ hist,
                                                   int ne, int nb, int nbuck) {
  __shared__ int lh[256];
  lh[threadIdx.x] = 0;
  __syncthreads();
  int base = blockIdx.x * EPBH;
#pragma unroll
  for (int j = 0; j < 16; ++j) {
    int e = base + j * 256 + threadIdx.x;
    if (e < ne) {
      int d = __builtin_nontemporal_load(&dst[e]);
      atomicAdd(&lh[d >> 8], 1);
    }
  }
  __syncthreads();
  if (threadIdx.x < nbuck)
    hist[(size_t)threadIdx.x * nb + blockIdx.x] = lh[threadIdx.x];
}

__global__ void scan_block(const int* __restrict__ in, int* __restrict__ part,
                           int* __restrict__ bsum, int n) {
  __shared__ int s[1024];
  int i = blockIdx.x * 1024 + threadIdx.x;
  int v = (i < n) ? in[i] : 0;
  s[threadIdx.x] = v;
  __syncthreads();
  for (int off = 1; off < 1024; off <<= 1) {
    int t = (threadIdx.x >= (unsigned)off) ? s[threadIdx.x - off] : 0;
    __syncthreads();
    s[threadIdx.x] += t;
    __syncthreads();
  }
  if (i < n) part[i] = s[threadIdx.x] - v;           // exclusive within block
  if (threadIdx.x == 1023) bsum[blockIdx.x] = s[1023];
}

__global__ void scan_partials(int* __restrict__ bsum, int nb) {  // nb <= 256
  __shared__ int s[256];
  int v = (threadIdx.x < (unsigned)nb) ? bsum[threadIdx.x] : 0;
  s[threadIdx.x] = v;
  __syncthreads();
  for (int off = 1; off < 256; off <<= 1) {
    int t = (threadIdx.x >= (unsigned)off) ? s[threadIdx.x - off] : 0;
    __syncthreads();
    s[threadIdx.x] += t;
    __syncthreads();
  }
  if (threadIdx.x < (unsigned)nb) bsum[threadIdx.x] = s[threadIdx.x] - v;
}

__global__ void finalize_scan(const int* __restrict__ part, const int* __restrict__ bsum,
                              int* __restrict__ out, int n) {
  int i = blockIdx.x * blockDim.x + threadIdx.x;
  if (i < n) out[i] = part[i] + bsum[i >> 10];
}

__global__ __launch_bounds__(256) void bucket_scatter(const int* __restrict__ src,
                                                      const int* __restrict__ dst,
                                                      const int* __restrict__ scanned,
                                                      uint2* __restrict__ ebuf,
                                                      int ne, int nb, int nbuck) {
  __shared__ int cur[256];
  if (threadIdx.x < nbuck)
    cur[threadIdx.x] = scanned[(size_t)threadIdx.x * nb + blockIdx.x];
  __syncthreads();
  int base = blockIdx.x * EPBH;
#pragma unroll
  for (int j = 0; j < 16; ++j) {
    int e = base + j * 256 + threadIdx.x;
    if (e < ne) {
      int s = __builtin_nontemporal_load(&src[e]);
      int d = __builtin_nontemporal_load(&dst[e]);
      int pos = atomicAdd(&cur[d >> 8], 1);   // LDS-scope
      ebuf[pos] = make_uint2((unsigned)s, (unsigned)d);
    }
  }
}

// One block per bucket: exact CSR slice + dinv, all in LDS.
__global__ __launch_bounds__(256) void bucket_csr(const uint2* __restrict__ ebuf,
                                                  const int* __restrict__ scanned,
                                                  int* __restrict__ row_ptr,
                                                  float* __restrict__ dinv,
                                                  int* __restrict__ col,
                                                  int ne, int nb, int nbuck, int n) {
  __shared__ int lcnt[256];
  __shared__ int lofs[256];
  __shared__ int cur[256];
  __shared__ uint2 sbuf[DCAP];
  int b = blockIdx.x;
  int start = scanned[(size_t)b * nb];
  int end = (b + 1 < nbuck) ? scanned[(size_t)(b + 1) * nb] : ne;
  lcnt[threadIdx.x] = 0;
  __syncthreads();
  for (int k = start + threadIdx.x; k < end; k += 256) {
    uint2 ed = ebuf[k];
    int rel = k - start;
    if (rel < DCAP) sbuf[rel] = ed;
    atomicAdd(&lcnt[ed.y & 255], 1);          // LDS-scope
  }
  __syncthreads();
  int v = lcnt[threadIdx.x];
  lofs[threadIdx.x] = v;
  __syncthreads();
  for (int off = 1; off < 256; off <<= 1) {
    int t = (threadIdx.x >= (unsigned)off) ? lofs[threadIdx.x - off] : 0;
    __syncthreads();
    lofs[threadIdx.x] += t;
    __syncthreads();
  }
  int excl = lofs[threadIdx.x] - v;
  int node = b * 256 + threadIdx.x;
  if (node < n) {
    row_ptr[node] = start + excl;
    dinv[node] = rsqrtf((float)(v + 1));      // +1 self-loop
  }
  cur[threadIdx.x] = start + excl;
  __syncthreads();
  for (int k = start + threadIdx.x; k < end; k += 256) {
    int rel = k - start;
    uint2 ed = (rel < DCAP) ? sbuf[rel] : ebuf[k];
    int pos = atomicAdd(&cur[ed.y & 255], 1); // LDS-scope
    col[pos] = (int)ed.x;
  }
  if (b == nbuck - 1 && threadIdx.x == 0) row_ptr[n] = ne;
}

// ---------------- GEMM (fp32 in, fp16 out, slice-contiguous layout) ----------------
// R8: output layout hsh4[slice][node][32feat] (slice = 3.2 MB) so each
// aggregate pass's gather set fits a 4 MB XCD L2.

__global__ __launch_bounds__(256) void gemm_scale_h(const float* __restrict__ in,
                                                    const float* __restrict__ W,
                                                    const float* __restrict__ dinv,
                                                    __half* __restrict__ out, int nrows) {
  __shared__ float ws[16][128];
  __shared__ float xs[64][17];
  int row0 = blockIdx.x * 64;
  int tid = threadIdx.x;
  int rg = tid >> 4;   // 0..15 -> rows rg*4..rg*4+3
  int cg = tid & 15;   // 0..15 -> cols cg*4 & 64+cg*4

  float acc[4][8] = {{0.f}};

  for (int k0 = 0; k0 < 128; k0 += 16) {
    {
      int idx = tid * 8;
      int kk = idx >> 7;
      int f = idx & 127;
      float4 a = *(const float4*)&W[(size_t)(k0 + kk) * 128 + f];
      float4 b = *(const float4*)&W[(size_t)(k0 + kk) * 128 + f + 4];
      *(float4*)&ws[kk][f] = a;
      *(float4*)&ws[kk][f + 4] = b;
    }
    {
      int idx = tid * 4;
      int r = idx >> 4;
      int kk = idx & 15;
      int grow = row0 + r;
      float4 v = make_float4(0.f, 0.f, 0.f, 0.f);
      if (grow < nrows) v = *(const float4*)&in[(size_t)grow * 128 + k0 + kk];
      xs[r][kk] = v.x; xs[r][kk + 1] = v.y; xs[r][kk + 2] = v.z; xs[r][kk + 3] = v.w;
    }
    __syncthreads();
#pragma unroll
    for (int kk = 0; kk < 16; ++kk) {
      float b0[8];
      *(float4*)&b0[0] = *(const float4*)&ws[kk][cg * 4];
      *(float4*)&b0[4] = *(const float4*)&ws[kk][64 + cg * 4];
      float a0 = xs[rg * 4 + 0][kk];
      float a1 = xs[rg * 4 + 1][kk];
      float a2 = xs[rg * 4 + 2][kk];
      float a3 = xs[rg * 4 + 3][kk];
#pragma unroll
      for (int j = 0; j < 8; ++j) {
        acc[0][j] += a0 * b0[j];
        acc[1][j] += a1 * b0[j];
        acc[2][j] += a2 * b0[j];
        acc[3][j] += a3 * b0[j];
      }
    }
    __syncthreads();
  }

  int c0 = cg * 4;        // slice c0>>5, offset c0&31
  int c1 = 64 + cg * 4;
#pragma unroll
  for (int r = 0; r < 4; ++r) {
    int grow = row0 + rg * 4 + r;
    if (grow < nrows) {
      float sc = dinv[grow];
      __half h[8];
#pragma unroll
      for (int j = 0; j < 8; ++j) h[j] = __float2half_rn(acc[r][j] * sc);
      *(uint2*)&out[((size_t)(c0 >> 5) * nrows + grow) * 32 + (c0 & 31)] = *(uint2*)&h[0];
      *(uint2*)&out[((size_t)(c1 >> 5) * nrows + grow) * 32 + (c1 & 31)] = *(uint2*)&h[4];
    }
  }
}

// ---------------- Slice-phased aggregation (R8) ----------------
// One pass per 32-feature slice; ALL blocks gather from the same 3.2 MB
// slice -> L2-resident on every XCD with no block->XCD mapping assumption
// (R3's failure). Lane = (e4, f): e4 = edge-in-group, f = uint (2 fp16) in
// the 64B row slice -> each gather instruction = 4 edges x 64B = 256B
// (R3's other failure was 64B/instr). col loaded once per 16 edges,
// distributed via shfl. col loads + all output stores nontemporal so
// streams don't evict the resident slice.

__global__ __launch_bounds__(256) void aggregate_pass_h(const __half* __restrict__ hsh4,
                                                        const int* __restrict__ row_ptr,
                                                        const int* __restrict__ col,
                                                        const float* __restrict__ dinv,
                                                        const float* __restrict__ bias,
                                                        float* __restrict__ out,
                                                        int n, int s) {
  int node = (blockIdx.x * blockDim.x + threadIdx.x) >> 6;
  if (node >= n) return;
  int lane = threadIdx.x & 63;
  int e4 = lane >> 4;
  int f = lane & 15;
  const uint* base = (const uint*)hsh4 + (size_t)s * n * 16;  // 16 uints/row

  int start = row_ptr[node];
  int end = row_ptr[node + 1];

  float2 acc = make_float2(0.f, 0.f);
  if (e4 == 0) {  // self-loop
    uint u = base[(size_t)node * 16 + f];
    acc = __half22float2(*(__half2*)&u);
  }

  int e = start;
  for (; e + 15 < end; e += 16) {
    int c = __builtin_nontemporal_load(&col[e + f]);
#pragma unroll
    for (int j = 0; j < 4; ++j) {
      int sn = __shfl(c, 4 * j + e4);
      uint u = base[(size_t)sn * 16 + f];
      float2 v = __half22float2(*(__half2*)&u);
      acc.x += v.x; acc.y += v.y;
    }
  }
  for (; e < end; e += 4) {
    int idx = e + e4;
    if (idx < end) {
      int sn = __builtin_nontemporal_load(&col[idx]);
      uint u = base[(size_t)sn * 16 + f];
      float2 v = __half22float2(*(__half2*)&u);
      acc.x += v.x; acc.y += v.y;
    }
  }

  acc.x += __shfl_xor(acc.x, 16);
  acc.y += __shfl_xor(acc.y, 16);
  acc.x += __shfl_xor(acc.x, 32);
  acc.y += __shfl_xor(acc.y, 32);

  if (e4 == 0) {
    float d = dinv[node];
    float2 b = *(const float2*)&bias[s * 32 + 2 * f];
    float* op = &out[(size_t)node * 128 + s * 32 + 2 * f];
    __builtin_nontemporal_store(fmaxf(acc.x * d + b.x, 0.f), op);
    __builtin_nontemporal_store(fmaxf(acc.y * d + b.y, 0.f), op + 1);
  }
}

// Layer-2 pass: fused partial dot with Wc -> partial[s][node] (deterministic
// cross-slice reduce in reduce_out; no atomics).

__global__ __launch_bounds__(256) void aggregate_dot_pass_h(const __half* __restrict__ hsh4,
                                                            const int* __restrict__ row_ptr,
                                                            const int* __restrict__ col,
                                                            const float* __restrict__ dinv,
                                                            const float* __restrict__ bias,
                                                            const float* __restrict__ Wc,
                                                            float* __restrict__ partial,
                                                            int n, int s) {
  int node = (blockIdx.x * blockDim.x + threadIdx.x) >> 6;
  if (node >= n) return;
  int lane = threadIdx.x & 63;
  int e4 = lane >> 4;
  int f = lane & 15;
  const uint* base = (const uint*)hsh4 + (size_t)s * n * 16;

  int start = row_ptr[node];
  int end = row_ptr[node + 1];

  float2 acc = make_float2(0.f, 0.f);
  if (e4 == 0) {  // self-loop
    uint u = base[(size_t)node * 16 + f];
    acc = __half22float2(*(__half2*)&u);
  }

  int e = start;
  for (; e + 15 < end; e += 16) {
    int c = __builtin_nontemporal_load(&col[e + f]);
#pragma unroll
    for (int j = 0; j < 4; ++j) {
      int sn = __shfl(c, 4 * j + e4);
      uint u = base[(size_t)sn * 16 + f];
      float2 v = __half22float2(*(__half2*)&u);
      acc.x += v.x; acc.y += v.y;
    }
  }
  for (; e < end; e += 4) {
    int idx = e + e4;
    if (idx < end) {
      int sn = __builtin_nontemporal_load(&col[idx]);
      uint u = base[(size_t)sn * 16 + f];
      float2 v = __half22float2(*(__half2*)&u);
      acc.x += v.x; acc.y += v.y;
    }
  }

  acc.x += __shfl_xor(acc.x, 16);
  acc.y += __shfl_xor(acc.y, 16);
  acc.x += __shfl_xor(acc.x, 32);
  acc.y += __shfl_xor(acc.y, 32);

  if (e4 == 0) {
    float d = dinv[node];
    float2 b = *(const float2*)&bias[s * 32 + 2 * f];
    float2 w = *(const float2*)&Wc[s * 32 + 2 * f];
    float p = fmaxf(acc.x * d + b.x, 0.f) * w.x + fmaxf(acc.y * d + b.y, 0.f) * w.y;
    p += __shfl_xor(p, 1);
    p += __shfl_xor(p, 2);
    p += __shfl_xor(p, 4);
    p += __shfl_xor(p, 8);
    if (f == 0) __builtin_nontemporal_store(p, &partial[(size_t)s * n + node]);
  }
}

__global__ void reduce_out(const float* __restrict__ partial, const float* __restrict__ bc,
                           float* __restrict__ out, int n) {
  int i = blockIdx.x * blockDim.x + threadIdx.x;
  if (i < n)
    out[i] = partial[i] + partial[(size_t)n + i] + partial[2 * (size_t)n + i] +
             partial[3 * (size_t)n + i] + bc[0];
}

// ---------------- launch ----------------

extern "C" void kernel_launch(void* const* d_in, const int* in_sizes, int n_in,
                              void* d_out, int out_size, void* d_ws, size_t ws_size,
                              hipStream_t stream) {
  const float* x  = (const float*)d_in[0];
  const int* ei   = (const int*)d_in[1];
  const float* W1 = (const float*)d_in[2];
  const float* b1 = (const float*)d_in[3];
  const float* W2 = (const float*)d_in[4];
  const float* b2 = (const float*)d_in[5];
  const float* Wc = (const float*)d_in[6];
  const float* bc = (const float*)d_in[7];
  float* out = (float*)d_out;

  int n  = in_sizes[0] / 128;
  int ne = in_sizes[1] / 2;
  const int* src = ei;
  const int* dst = ei + ne;

  int NBb = (ne + EPBH - 1) / EPBH;      // 391 hist/scatter blocks
  int NBUCK = (n + 255) >> 8;            // 196 buckets (requires n <= 65536)
  int HN = NBUCK * NBb;                  // 76,636 hist entries

  char* p = (char*)d_ws;
  auto alloc = [&](size_t bytes) {
    char* r = p;
    p += (bytes + 255) & ~(size_t)255;
    return r;
  };
  int*    hist    = (int*)alloc((size_t)HN * 4);
  int*    part    = (int*)alloc((size_t)HN * 4);
  int*    bsum    = (int*)alloc(256 * 4);
  int*    row_ptr = (int*)alloc((size_t)(n + 1) * 4);
  float*  dinv    = (float*)alloc((size_t)n * 4);
  int*    col     = (int*)alloc((size_t)ne * 4);
  float*  partial = (float*)alloc((size_t)n * 4 * 4);     // [4][n] layer-2 dots
  __half* hsh4    = (__half*)alloc((size_t)n * 128 * 2);  // [4][n][32] fp16
  float*  h1      = (float*)alloc((size_t)n * 128 * 4);   // fp32 layer-1 output
  // ebuf aliases h1: ebuf (ne*8 = 12.8 MB <= 25.6 MB) is dead after
  // bucket_csr; h1 first written by aggregate_pass_h, strictly later.
  uint2*  ebuf    = (uint2*)h1;

  bucket_hist<<<NBb, 256, 0, stream>>>(dst, hist, ne, NBb, NBUCK);
  int nsb = (HN + 1023) / 1024;          // 75 <= 256
  scan_block<<<nsb, 1024, 0, stream>>>(hist, part, bsum, HN);
  scan_partials<<<1, 256, 0, stream>>>(bsum, nsb);
  finalize_scan<<<(HN + 255) / 256, 256, 0, stream>>>(part, bsum, hist, HN);
  bucket_scatter<<<NBb, 256, 0, stream>>>(src, dst, hist, ebuf, ne, NBb, NBUCK);
  bucket_csr<<<NBUCK, 256, 0, stream>>>(ebuf, hist, row_ptr, dinv, col, ne, NBb, NBUCK, n);

  int gemm_blocks = (n + 63) / 64;
  int agg_blocks = (n + 3) / 4;  // 4 waves/block, 1 wave/node

  gemm_scale_h<<<gemm_blocks, 256, 0, stream>>>(x, W1, dinv, hsh4, n);
  for (int s = 0; s < 4; ++s)
    aggregate_pass_h<<<agg_blocks, 256, 0, stream>>>(hsh4, row_ptr, col, dinv, b1, h1, n, s);
  gemm_scale_h<<<gemm_blocks, 256, 0, stream>>>(h1, W2, dinv, hsh4, n);
  for (int s = 0; s < 4; ++s)
    aggregate_dot_pass_h<<<agg_blocks, 256, 0, stream>>>(hsh4, row_ptr, col, dinv, b2, Wc,
                                                         partial, n, s);
  reduce_out<<<(n + 255) / 256, 256, 0, stream>>>(partial, bc, out, n);
}

// Round 10
// 226.238 us; speedup vs baseline: 1.7142x; 1.7142x over previous
//
#include <hip/hip_runtime.h>
#include <hip/hip_fp16.h>
#include <cstdint>

// ---------------- CSR build: atomic-free bucketed counting sort (R7, proven) ----------------

#define EPBH 4096   // edges per block in hist/scatter passes (256 thr x 16)
#define DCAP 9216   // LDS staging capacity in bucket_csr (mean ~8163 edges)

__global__ __launch_bounds__(256) void bucket_hist(const int* __restrict__ dst,
                                                   int* __restrict__ hist,
                                                   int ne, int nb, int nbuck) {
  __shared__ int lh[256];
  lh[threadIdx.x] = 0;
  __syncthreads();
  int base = blockIdx.x * EPBH;
#pragma unroll
  for (int j = 0; j < 16; ++j) {
    int e = base + j * 256 + threadIdx.x;
    if (e < ne) {
      int d = __builtin_nontemporal_load(&dst[e]);
      atomicAdd(&lh[d >> 8], 1);
    }
  }
  __syncthreads();
  if (threadIdx.x < nbuck)
    hist[(size_t)threadIdx.x * nb + blockIdx.x] = lh[threadIdx.x];
}

__global__ void scan_block(const int* __restrict__ in, int* __restrict__ part,
                           int* __restrict__ bsum, int n) {
  __shared__ int s[1024];
  int i = blockIdx.x * 1024 + threadIdx.x;
  int v = (i < n) ? in[i] : 0;
  s[threadIdx.x] = v;
  __syncthreads();
  for (int off = 1; off < 1024; off <<= 1) {
    int t = (threadIdx.x >= (unsigned)off) ? s[threadIdx.x - off] : 0;
    __syncthreads();
    s[threadIdx.x] += t;
    __syncthreads();
  }
  if (i < n) part[i] = s[threadIdx.x] - v;           // exclusive within block
  if (threadIdx.x == 1023) bsum[blockIdx.x] = s[1023];
}

__global__ void scan_partials(int* __restrict__ bsum, int nb) {  // nb <= 256
  __shared__ int s[256];
  int v = (threadIdx.x < (unsigned)nb) ? bsum[threadIdx.x] : 0;
  s[threadIdx.x] = v;
  __syncthreads();
  for (int off = 1; off < 256; off <<= 1) {
    int t = (threadIdx.x >= (unsigned)off) ? s[threadIdx.x - off] : 0;
    __syncthreads();
    s[threadIdx.x] += t;
    __syncthreads();
  }
  if (threadIdx.x < (unsigned)nb) bsum[threadIdx.x] = s[threadIdx.x] - v;
}

__global__ void finalize_scan(const int* __restrict__ part, const int* __restrict__ bsum,
                              int* __restrict__ out, int n) {
  int i = blockIdx.x * blockDim.x + threadIdx.x;
  if (i < n) out[i] = part[i] + bsum[i >> 10];
}

__global__ __launch_bounds__(256) void bucket_scatter(const int* __restrict__ src,
                                                      const int* __restrict__ dst,
                                                      const int* __restrict__ scanned,
                                                      uint2* __restrict__ ebuf,
                                                      int ne, int nb, int nbuck) {
  __shared__ int cur[256];
  if (threadIdx.x < nbuck)
    cur[threadIdx.x] = scanned[(size_t)threadIdx.x * nb + blockIdx.x];
  __syncthreads();
  int base = blockIdx.x * EPBH;
#pragma unroll
  for (int j = 0; j < 16; ++j) {
    int e = base + j * 256 + threadIdx.x;
    if (e < ne) {
      int s = __builtin_nontemporal_load(&src[e]);
      int d = __builtin_nontemporal_load(&dst[e]);
      int pos = atomicAdd(&cur[d >> 8], 1);   // LDS-scope
      ebuf[pos] = make_uint2((unsigned)s, (unsigned)d);
    }
  }
}

// One block per bucket: exact CSR slice + dinv, all in LDS.
__global__ __launch_bounds__(256) void bucket_csr(const uint2* __restrict__ ebuf,
                                                  const int* __restrict__ scanned,
                                                  int* __restrict__ row_ptr,
                                                  float* __restrict__ dinv,
                                                  int* __restrict__ col,
                                                  int ne, int nb, int nbuck, int n) {
  __shared__ int lcnt[256];
  __shared__ int lofs[256];
  __shared__ int cur[256];
  __shared__ uint2 sbuf[DCAP];
  int b = blockIdx.x;
  int start = scanned[(size_t)b * nb];
  int end = (b + 1 < nbuck) ? scanned[(size_t)(b + 1) * nb] : ne;
  lcnt[threadIdx.x] = 0;
  __syncthreads();
  for (int k = start + threadIdx.x; k < end; k += 256) {
    uint2 ed = ebuf[k];
    int rel = k - start;
    if (rel < DCAP) sbuf[rel] = ed;
    atomicAdd(&lcnt[ed.y & 255], 1);          // LDS-scope
  }
  __syncthreads();
  int v = lcnt[threadIdx.x];
  lofs[threadIdx.x] = v;
  __syncthreads();
  for (int off = 1; off < 256; off <<= 1) {
    int t = (threadIdx.x >= (unsigned)off) ? lofs[threadIdx.x - off] : 0;
    __syncthreads();
    lofs[threadIdx.x] += t;
    __syncthreads();
  }
  int excl = lofs[threadIdx.x] - v;
  int node = b * 256 + threadIdx.x;
  if (node < n) {
    row_ptr[node] = start + excl;
    dinv[node] = rsqrtf((float)(v + 1));      // +1 self-loop
  }
  cur[threadIdx.x] = start + excl;
  __syncthreads();
  for (int k = start + threadIdx.x; k < end; k += 256) {
    int rel = k - start;
    uint2 ed = (rel < DCAP) ? sbuf[rel] : ebuf[k];
    int pos = atomicAdd(&cur[ed.y & 255], 1); // LDS-scope
    col[pos] = (int)ed.x;
  }
  if (b == nbuck - 1 && threadIdx.x == 0) row_ptr[n] = ne;
}

// ---------------- MFMA fp16 GEMM (R10) fused with dinv pre-scale ----------------
// C[i][f] = (sum_k in[i][k] W[k][f]) * dinv[i], out fp16.
// Tile: block = 64 rows x 128 cols, 4 waves, wave = 16 rows x 128 cols.
// v_mfma_f32_16x16x32_f16: A/B frag = 8 f16/lane (k = (lane>>4)*8 + i);
// C/D: col = lane&15, row = (lane>>4)*4 + reg  [m89-verified, dtype-indep].
// LDS rows padded to 136 halfs -> ds_read_b128 is 2-way bank-aliased (free).

typedef _Float16 half_t;
typedef __attribute__((ext_vector_type(8))) _Float16 f16x8;
typedef __attribute__((ext_vector_type(4))) float f32x4;

#define LDP 136

__global__ __launch_bounds__(256) void gemm_mfma_h(const float* __restrict__ in,
                                                   const float* __restrict__ W,
                                                   const float* __restrict__ dinv,
                                                   __half* __restrict__ out, int nrows) {
  __shared__ half_t As[64][LDP];    // A tile: 64 rows x 128 k
  __shared__ half_t Bs[128][LDP];   // W^T: Bs[f][k]
  int tid = threadIdx.x;
  int row0 = blockIdx.x * 64;

  // stage W^T (fp32 -> fp16): 128x128, 16 float4 per thread
#pragma unroll
  for (int it = 0; it < 16; ++it) {
    int idx = it * 256 + tid;       // 0..4095
    int k = idx >> 5;               // 0..127
    int f4 = (idx & 31) * 4;        // 0..124
    float4 w = *(const float4*)&W[(size_t)k * 128 + f4];
    Bs[f4 + 0][k] = (half_t)w.x;
    Bs[f4 + 1][k] = (half_t)w.y;
    Bs[f4 + 2][k] = (half_t)w.z;
    Bs[f4 + 3][k] = (half_t)w.w;
  }
  // stage A (fp32 -> fp16): 64 rows x 128 k, 8 float4 per thread
#pragma unroll
  for (int it = 0; it < 8; ++it) {
    int idx = it * 256 + tid;       // 0..2047
    int r = idx >> 5;
    int k4 = (idx & 31) * 4;
    int grow = row0 + r;
    float4 v = make_float4(0.f, 0.f, 0.f, 0.f);
    if (grow < nrows) v = *(const float4*)&in[(size_t)grow * 128 + k4];
    As[r][k4 + 0] = (half_t)v.x;
    As[r][k4 + 1] = (half_t)v.y;
    As[r][k4 + 2] = (half_t)v.z;
    As[r][k4 + 3] = (half_t)v.w;
  }
  __syncthreads();

  int wv = tid >> 6;                // wave -> rows wv*16
  int lane = tid & 63;
  int m = lane & 15;
  int kg = lane >> 4;               // 0..3

  f32x4 acc[8];
#pragma unroll
  for (int ct = 0; ct < 8; ++ct) acc[ct] = (f32x4){0.f, 0.f, 0.f, 0.f};

#pragma unroll
  for (int ks = 0; ks < 4; ++ks) {  // K = 4 x 32
    f16x8 a = *(const f16x8*)&As[wv * 16 + m][ks * 32 + kg * 8];
#pragma unroll
    for (int ct = 0; ct < 8; ++ct) {
      f16x8 b = *(const f16x8*)&Bs[ct * 16 + m][ks * 32 + kg * 8];
      acc[ct] = __builtin_amdgcn_mfma_f32_16x16x32_f16(a, b, acc[ct], 0, 0, 0);
    }
  }

  int orow = row0 + wv * 16 + kg * 4;
  float d0 = (orow + 0 < nrows) ? dinv[orow + 0] : 0.f;
  float d1 = (orow + 1 < nrows) ? dinv[orow + 1] : 0.f;
  float d2 = (orow + 2 < nrows) ? dinv[orow + 2] : 0.f;
  float d3 = (orow + 3 < nrows) ? dinv[orow + 3] : 0.f;
#pragma unroll
  for (int ct = 0; ct < 8; ++ct) {
    int ocol = ct * 16 + m;
    if (orow + 0 < nrows) out[(size_t)(orow + 0) * 128 + ocol] = __float2half_rn(acc[ct][0] * d0);
    if (orow + 1 < nrows) out[(size_t)(orow + 1) * 128 + ocol] = __float2half_rn(acc[ct][1] * d1);
    if (orow + 2 < nrows) out[(size_t)(orow + 2) * 128 + ocol] = __float2half_rn(acc[ct][2] * d2);
    if (orow + 3 < nrows) out[(size_t)(orow + 3) * 128 + ocol] = __float2half_rn(acc[ct][3] * d3);
  }
}

// ---------------- fp16 row gather helpers ----------------

__device__ inline float4 h4_to_f4(uint2 u) {
  __half2 a = *(__half2*)&u.x;
  __half2 b = *(__half2*)&u.y;
  float2 fa = __half22float2(a);
  float2 fb = __half22float2(b);
  return make_float4(fa.x, fa.y, fb.x, fb.y);
}

// ---------------- Aggregation (R7, proven): 1 node/wave, half-wave = 256B fp16 row ----------------
// 16 edges / 4 KB outstanding per wave (R3/R9 lesson: maximize bytes in flight).

__global__ __launch_bounds__(256) void aggregate_h(const __half* __restrict__ hsh,
                                                   const int* __restrict__ row_ptr,
                                                   const int* __restrict__ col,
                                                   const float* __restrict__ dinv,
                                                   const float* __restrict__ bias,
                                                   float* __restrict__ out, int n) {
  int node = (blockIdx.x * blockDim.x + threadIdx.x) >> 6;
  if (node >= n) return;
  int lane = threadIdx.x & 63;
  int half_ = lane >> 5;
  int f4 = lane & 31;
  const uint2* rows = (const uint2*)hsh;  // row stride = 32 uint2

  int start = row_ptr[node];
  int end = row_ptr[node + 1];

  float4 acc = make_float4(0.f, 0.f, 0.f, 0.f);
  if (half_ == 0) acc = h4_to_f4(rows[(size_t)node * 32 + f4]);  // self-loop

  int e = start + half_;
  for (; e + 14 < end; e += 16) {
    uint2 u[8];
#pragma unroll
    for (int j = 0; j < 8; ++j) u[j] = rows[(size_t)col[e + 2 * j] * 32 + f4];
#pragma unroll
    for (int j = 0; j < 8; ++j) {
      float4 v = h4_to_f4(u[j]);
      acc.x += v.x; acc.y += v.y; acc.z += v.z; acc.w += v.w;
    }
  }
  for (; e < end; e += 2) {
    float4 v = h4_to_f4(rows[(size_t)col[e] * 32 + f4]);
    acc.x += v.x; acc.y += v.y; acc.z += v.z; acc.w += v.w;
  }

  acc.x += __shfl_xor(acc.x, 32);
  acc.y += __shfl_xor(acc.y, 32);
  acc.z += __shfl_xor(acc.z, 32);
  acc.w += __shfl_xor(acc.w, 32);

  if (half_ == 0) {
    float d = dinv[node];
    float4 b = ((const float4*)bias)[f4];
    float4 o;
    o.x = fmaxf(acc.x * d + b.x, 0.f);
    o.y = fmaxf(acc.y * d + b.y, 0.f);
    o.z = fmaxf(acc.z * d + b.z, 0.f);
    o.w = fmaxf(acc.w * d + b.w, 0.f);
    ((float4*)out)[(size_t)node * 32 + f4] = o;
  }
}

// Layer-2 variant: same gather, fused 128->1 projection with Wc.

__global__ __launch_bounds__(256) void aggregate_dot_h(const __half* __restrict__ hsh,
                                                       const int* __restrict__ row_ptr,
                                                       const int* __restrict__ col,
                                                       const float* __restrict__ dinv,
                                                       const float* __restrict__ bias,
                                                       const float* __restrict__ Wc,
                                                       const float* __restrict__ bc,
                                                       float* __restrict__ out, int n) {
  int node = (blockIdx.x * blockDim.x + threadIdx.x) >> 6;
  if (node >= n) return;
  int lane = threadIdx.x & 63;
  int half_ = lane >> 5;
  int f4 = lane & 31;
  const uint2* rows = (const uint2*)hsh;

  int start = row_ptr[node];
  int end = row_ptr[node + 1];

  float4 acc = make_float4(0.f, 0.f, 0.f, 0.f);
  if (half_ == 0) acc = h4_to_f4(rows[(size_t)node * 32 + f4]);  // self-loop

  int e = start + half_;
  for (; e + 14 < end; e += 16) {
    uint2 u[8];
#pragma unroll
    for (int j = 0; j < 8; ++j) u[j] = rows[(size_t)col[e + 2 * j] * 32 + f4];
#pragma unroll
    for (int j = 0; j < 8; ++j) {
      float4 v = h4_to_f4(u[j]);
      acc.x += v.x; acc.y += v.y; acc.z += v.z; acc.w += v.w;
    }
  }
  for (; e < end; e += 2) {
    float4 v = h4_to_f4(rows[(size_t)col[e] * 32 + f4]);
    acc.x += v.x; acc.y += v.y; acc.z += v.z; acc.w += v.w;
  }

  acc.x += __shfl_xor(acc.x, 32);
  acc.y += __shfl_xor(acc.y, 32);
  acc.z += __shfl_xor(acc.z, 32);
  acc.w += __shfl_xor(acc.w, 32);

  float d = dinv[node];
  float4 b = ((const float4*)bias)[f4];
  float4 w = ((const float4*)Wc)[f4];
  float s = fmaxf(acc.x * d + b.x, 0.f) * w.x
          + fmaxf(acc.y * d + b.y, 0.f) * w.y
          + fmaxf(acc.z * d + b.z, 0.f) * w.z
          + fmaxf(acc.w * d + b.w, 0.f) * w.w;
#pragma unroll
  for (int off = 16; off; off >>= 1) s += __shfl_xor(s, off);
  if (lane == 0) out[node] = s + bc[0];
}

// ---------------- launch ----------------

extern "C" void kernel_launch(void* const* d_in, const int* in_sizes, int n_in,
                              void* d_out, int out_size, void* d_ws, size_t ws_size,
                              hipStream_t stream) {
  const float* x  = (const float*)d_in[0];
  const int* ei   = (const int*)d_in[1];
  const float* W1 = (const float*)d_in[2];
  const float* b1 = (const float*)d_in[3];
  const float* W2 = (const float*)d_in[4];
  const float* b2 = (const float*)d_in[5];
  const float* Wc = (const float*)d_in[6];
  const float* bc = (const float*)d_in[7];
  float* out = (float*)d_out;

  int n  = in_sizes[0] / 128;
  int ne = in_sizes[1] / 2;
  const int* src = ei;
  const int* dst = ei + ne;

  int NBb = (ne + EPBH - 1) / EPBH;      // 391 hist/scatter blocks
  int NBUCK = (n + 255) >> 8;            // 196 buckets (requires n <= 65536)
  int HN = NBUCK * NBb;                  // 76,636 hist entries

  char* p = (char*)d_ws;
  auto alloc = [&](size_t bytes) {
    char* r = p;
    p += (bytes + 255) & ~(size_t)255;
    return r;
  };
  int*    hist    = (int*)alloc((size_t)HN * 4);
  int*    part    = (int*)alloc((size_t)HN * 4);
  int*    bsum    = (int*)alloc(256 * 4);
  int*    row_ptr = (int*)alloc((size_t)(n + 1) * 4);
  float*  dinv    = (float*)alloc((size_t)n * 4);
  int*    col     = (int*)alloc((size_t)ne * 4);
  __half* hsh     = (__half*)alloc((size_t)n * 128 * 2);  // fp16 GEMM output
  float*  h1      = (float*)alloc((size_t)n * 128 * 4);   // fp32 layer-1 output
  // ebuf aliases h1: ebuf (ne*8 = 12.8 MB <= 25.6 MB) is dead after
  // bucket_csr; h1 first written by aggregate_h, strictly later on stream.
  uint2*  ebuf    = (uint2*)h1;

  bucket_hist<<<NBb, 256, 0, stream>>>(dst, hist, ne, NBb, NBUCK);
  int nsb = (HN + 1023) / 1024;          // 75 <= 256
  scan_block<<<nsb, 1024, 0, stream>>>(hist, part, bsum, HN);
  scan_partials<<<1, 256, 0, stream>>>(bsum, nsb);
  finalize_scan<<<(HN + 255) / 256, 256, 0, stream>>>(part, bsum, hist, HN);
  bucket_scatter<<<NBb, 256, 0, stream>>>(src, dst, hist, ebuf, ne, NBb, NBUCK);
  bucket_csr<<<NBUCK, 256, 0, stream>>>(ebuf, hist, row_ptr, dinv, col, ne, NBb, NBUCK, n);

  int gemm_blocks = (n + 63) / 64;
  int agg_blocks = (n + 3) / 4;  // 4 waves/block, 1 wave/node

  gemm_mfma_h<<<gemm_blocks, 256, 0, stream>>>(x, W1, dinv, hsh, n);
  aggregate_h<<<agg_blocks, 256, 0, stream>>>(hsh, row_ptr, col, dinv, b1, h1, n);
  gemm_mfma_h<<<gemm_blocks, 256, 0, stream>>>(h1, W2, dinv, hsh, n);  // reuse hsh
  aggregate_dot_h<<<agg_blocks, 256, 0, stream>>>(hsh, row_ptr, col, dinv, b2, Wc, bc, out, n);
}